// Round 3
// baseline (1265.800 us; speedup 1.0000x reference)
//
#include <hip/hip_runtime.h>
#include <math.h>

#define N_NODES  100000
#define N_EDGES  3200000
#define N_GRAPHS 512
#define N_FEAT   128
#define DIM      10
#define PDIM     12      // padded p-row stride (floats), 48B, 16B-aligned
#define OUT      16
#define NBLK     ((N_NODES + 255) / 256)

#define BW       128                         // nodes per bucket
#define BSHIFT   7
#define NBUCK    ((N_NODES + BW - 1) / BW)   // 782
#define NBLK_E   512                         // blocks in edge passes
#define EPB      ((N_EDGES + NBLK_E - 1) / NBLK_E)  // 6250

// gptr[g] = first node with batch >= g (batch sorted). gptr[N_GRAPHS] = N_NODES.
__global__ void k_bounds(const int* __restrict__ batch, int* __restrict__ gptr) {
    int n = blockIdx.x * blockDim.x + threadIdx.x;
    if (n >= N_NODES) return;
    int bn = batch[n];
    int bp = (n == 0) ? -1 : batch[n - 1];
    for (int g = bp + 1; g <= bn; ++g) gptr[g] = n;
    if (n == N_NODES - 1)
        for (int g = bn + 1; g <= N_GRAPHS; ++g) gptr[g] = N_NODES;
}

// p[n][f] = sum_j x[n][j] * w1[j][f]  (128 -> 10), one wave per node
__global__ void k_proj1(const float* __restrict__ x, const float* __restrict__ w1,
                        float* __restrict__ p) {
    int wid  = (blockIdx.x * blockDim.x + threadIdx.x) >> 6;
    int lane = threadIdx.x & 63;
    if (wid >= N_NODES) return;
    float x1 = x[wid * N_FEAT + lane];
    float x2 = x[wid * N_FEAT + 64 + lane];
    float acc[DIM];
#pragma unroll
    for (int f = 0; f < DIM; ++f)
        acc[f] = x1 * w1[lane * DIM + f] + x2 * w1[(lane + 64) * DIM + f];
#pragma unroll
    for (int f = 0; f < DIM; ++f) {
        float v = acc[f];
        v += __shfl_xor(v, 32); v += __shfl_xor(v, 16); v += __shfl_xor(v, 8);
        v += __shfl_xor(v, 4);  v += __shfl_xor(v, 2);  v += __shfl_xor(v, 1);
        acc[f] = v;
    }
    if (lane == 0) {
#pragma unroll
        for (int f = 0; f < DIM; ++f) p[wid * PDIM + f] = acc[f];
    }
}

// ---- deterministic bucket sort of edges by dst>>BSHIFT (no global atomics) ----
// hist[b * NBLK_E + blk] = count of block blk's edges in bucket b
__global__ void k_hist(const int* __restrict__ ei, int* __restrict__ hist) {
    __shared__ int s_h[NBUCK];
    for (int i = threadIdx.x; i < NBUCK; i += blockDim.x) s_h[i] = 0;
    __syncthreads();
    int base = blockIdx.x * EPB;
    int end  = min(base + EPB, N_EDGES);
    for (int e = base + threadIdx.x; e < end; e += blockDim.x)
        atomicAdd(&s_h[ei[N_EDGES + e] >> BSHIFT], 1);
    __syncthreads();
    for (int i = threadIdx.x; i < NBUCK; i += blockDim.x)
        hist[i * NBLK_E + blockIdx.x] = s_h[i];
}

// bbase = exclusive scan of per-bucket totals; bbase[NBUCK] = N_EDGES
__global__ void k_bscan(const int* __restrict__ hist, int* __restrict__ bbase) {
    __shared__ int s[1024];
    int tid = threadIdx.x;
    for (int b = tid; b < NBUCK; b += 1024) {
        int t = 0;
        for (int k = 0; k < NBLK_E; ++k) t += hist[b * NBLK_E + k];
        bbase[b] = t;
    }
    __syncthreads();
    int v = (tid < NBUCK) ? bbase[tid] : 0;
    s[tid] = v;
    __syncthreads();
    for (int off = 1; off < 1024; off <<= 1) {
        int w = (tid >= off) ? s[tid - off] : 0;
        __syncthreads();
        s[tid] += w;
        __syncthreads();
    }
    if (tid < NBUCK) bbase[tid] = s[tid] - v;   // exclusive
    if (tid == 0)    bbase[NBUCK] = s[1023];    // total
}

// in-place: hist[b][blk] -> global base offset for (bucket b, block blk)
__global__ void k_colscan(int* __restrict__ hist, const int* __restrict__ bbase) {
    __shared__ int s[NBLK_E];
    int b = blockIdx.x, tid = threadIdx.x;
    int v = hist[b * NBLK_E + tid];
    s[tid] = v;
    __syncthreads();
    for (int off = 1; off < NBLK_E; off <<= 1) {
        int w = (tid >= off) ? s[tid - off] : 0;
        __syncthreads();
        s[tid] += w;
        __syncthreads();
    }
    hist[b * NBLK_E + tid] = bbase[b] + s[tid] - v;
}

// scatter edges into bucket-grouped ebuf; pos allocation via per-block LDS counters
__global__ void k_bucket(const int* __restrict__ ei, const int* __restrict__ off,
                         int* __restrict__ ebuf) {
    __shared__ int loc[NBUCK];
    for (int i = threadIdx.x; i < NBUCK; i += blockDim.x)
        loc[i] = off[i * NBLK_E + blockIdx.x];
    __syncthreads();
    int base = blockIdx.x * EPB;
    int end  = min(base + EPB, N_EDGES);
    for (int e = base + threadIdx.x; e < end; e += blockDim.x) {
        int src = ei[e];
        int dst = ei[N_EDGES + e];
        int bkt = dst >> BSHIFT;
        int pos = atomicAdd(&loc[bkt], 1);         // LDS atomic
        ebuf[pos] = ((dst & (BW - 1)) << 17) | src;
    }
}

// ---- fused per-bucket aggregation (LDS) + GIN MLP + next-layer projection ----
template <int HAS_NEXT>
__global__ void k_layer(const float* __restrict__ p, const int* __restrict__ bbase,
                        const int* __restrict__ ebuf,
                        const float* __restrict__ b1, const float* __restrict__ w2,
                        const float* __restrict__ b2, const float* __restrict__ w1n,
                        float* __restrict__ h, float* __restrict__ pn) {
    __shared__ float s_agg[BW * DIM];
    __shared__ float s_w2[DIM * DIM], s_w1n[DIM * DIM], s_b1[DIM], s_b2[DIM];
    int tid = threadIdx.x;
    if (tid < DIM * DIM) {
        s_w2[tid] = w2[tid];
        if (HAS_NEXT) s_w1n[tid] = w1n[tid];
    }
    if (tid < DIM) { s_b1[tid] = b1[tid]; s_b2[tid] = b2[tid]; }
    for (int i = tid; i < BW * DIM; i += blockDim.x) s_agg[i] = 0.f;
    __syncthreads();

    int beg = bbase[blockIdx.x], end = bbase[blockIdx.x + 1];
    for (int j = beg + tid; j < end; j += blockDim.x) {
        int pk  = ebuf[j];
        int src = pk & 0x1FFFF;
        int ld  = pk >> 17;
        const float4* q = (const float4*)&p[src * PDIM];
        float4 a0 = q[0], a1 = q[1];
        float2 a2 = *(const float2*)&p[src * PDIM + 8];
        float* ag = &s_agg[ld * DIM];
        atomicAdd(&ag[0], a0.x); atomicAdd(&ag[1], a0.y);
        atomicAdd(&ag[2], a0.z); atomicAdd(&ag[3], a0.w);
        atomicAdd(&ag[4], a1.x); atomicAdd(&ag[5], a1.y);
        atomicAdd(&ag[6], a1.z); atomicAdd(&ag[7], a1.w);
        atomicAdd(&ag[8], a2.x); atomicAdd(&ag[9], a2.y);
    }
    __syncthreads();

    int n = blockIdx.x * BW + tid;
    if (tid < BW && n < N_NODES) {
        const float4* q = (const float4*)&p[n * PDIM];
        float4 a0 = q[0], a1 = q[1];
        float2 a2 = *(const float2*)&p[n * PDIM + 8];
        float own[DIM] = {a0.x, a0.y, a0.z, a0.w, a1.x, a1.y, a1.z, a1.w, a2.x, a2.y};
        float u[DIM];
#pragma unroll
        for (int f = 0; f < DIM; ++f)
            u[f] = fmaxf(own[f] + s_agg[tid * DIM + f] + s_b1[f], 0.f);
        float hv[DIM];
#pragma unroll
        for (int f = 0; f < DIM; ++f) {
            float v = s_b2[f];
#pragma unroll
            for (int j = 0; j < DIM; ++j) v += u[j] * s_w2[j * DIM + f];
            hv[f] = fmaxf(v, 0.f);
            h[n * DIM + f] = hv[f];
        }
        if (HAS_NEXT) {
#pragma unroll
            for (int f = 0; f < DIM; ++f) {
                float v = 0.f;
#pragma unroll
                for (int j = 0; j < DIM; ++j) v += hv[j] * s_w1n[j * DIM + f];
                pn[n * PDIM + f] = v;
            }
        }
    }
}

// per-graph sum of h over contiguous node range
__global__ void k_pool(const float* __restrict__ h, const int* __restrict__ gptr,
                       float* __restrict__ pool) {
    int g = blockIdx.x;
    int s = gptr[g], e = gptr[g + 1];
    float acc[DIM];
#pragma unroll
    for (int f = 0; f < DIM; ++f) acc[f] = 0.f;
    for (int n = s + threadIdx.x; n < e; n += blockDim.x) {
#pragma unroll
        for (int f = 0; f < DIM; ++f) acc[f] += h[n * DIM + f];
    }
#pragma unroll
    for (int f = 0; f < DIM; ++f) {
        float v = acc[f];
        v += __shfl_xor(v, 32); v += __shfl_xor(v, 16); v += __shfl_xor(v, 8);
        v += __shfl_xor(v, 4);  v += __shfl_xor(v, 2);  v += __shfl_xor(v, 1);
        acc[f] = v;
    }
    __shared__ float s_red[4][DIM];
    int wave = threadIdx.x >> 6, lane = threadIdx.x & 63;
    if (lane == 0) {
#pragma unroll
        for (int f = 0; f < DIM; ++f) s_red[wave][f] = acc[f];
    }
    __syncthreads();
    if (threadIdx.x < DIM) {
        pool[g * DIM + threadIdx.x] = s_red[0][threadIdx.x] + s_red[1][threadIdx.x] +
                                      s_red[2][threadIdx.x] + s_red[3][threadIdx.x];
    }
}

__global__ void k_out(const float* __restrict__ pool, const int* __restrict__ gptr,
                      const float* __restrict__ l1, const float* __restrict__ l2,
                      const float* __restrict__ l3, const float* __restrict__ l4,
                      const float* __restrict__ l5, float* __restrict__ out) {
    int t = blockIdx.x * blockDim.x + threadIdx.x;
    if (t >= N_GRAPHS * OUT) return;
    int g = t >> 4;
    int o = t & 15;
    float cnt = fmaxf((float)(gptr[g + 1] - gptr[g]), 1.f);
    const float* ls[5] = {l1, l2, l3, l4, l5};
    float acc = 0.f;
#pragma unroll
    for (int l = 0; l < 5; ++l)
#pragma unroll
        for (int f = 0; f < DIM; ++f)
            acc += pool[(l * N_GRAPHS + g) * DIM + f] * ls[l][f * OUT + o];
    out[t] = tanhf(acc / cnt);
}

extern "C" void kernel_launch(void* const* d_in, const int* in_sizes, int n_in,
                              void* d_out, int out_size, void* d_ws, size_t ws_size,
                              hipStream_t stream) {
    const float* x     = (const float*)d_in[0];
    const int*   ei    = (const int*)d_in[1];
    const int*   batch = (const int*)d_in[2];
    const float *w1[5], *b1[5], *w2[5], *b2[5], *lp[5];
    for (int l = 0; l < 5; ++l) {
        w1[l] = (const float*)d_in[3 + l * 4 + 0];
        b1[l] = (const float*)d_in[3 + l * 4 + 1];
        w2[l] = (const float*)d_in[3 + l * 4 + 2];
        b2[l] = (const float*)d_in[3 + l * 4 + 3];
        lp[l] = (const float*)d_in[23 + l];
    }
    float* out = (float*)d_out;

    // workspace (floats/ints), ~26.5 MB total
    float* pA    = (float*)d_ws;                       // N*PDIM = 1,200,000
    float* pB    = pA + N_NODES * PDIM;                // 1,200,000
    float* h     = pB + N_NODES * PDIM;                // 1,000,000
    float* pool  = h + N_NODES * DIM;                  // 25,600
    int*   gptr  = (int*)(pool + 5 * N_GRAPHS * DIM);  // 513 -> pad 516
    int*   bbase = gptr + 516;                         // NBUCK+1 = 783 -> pad 784
    int*   ebuf  = bbase + 784;                        // N_EDGES
    int*   hist  = (int*)pB;  // aliased: NBUCK*NBLK_E = 400,384 ints, used only pre-layers

    k_bounds<<<NBLK, 256, 0, stream>>>(batch, gptr);
    k_proj1<<<(N_NODES * 64 + 255) / 256, 256, 0, stream>>>(x, w1[0], pA);

    // deterministic bucket sort of edges by dst bucket
    k_hist<<<NBLK_E, 512, 0, stream>>>(ei, hist);
    k_bscan<<<1, 1024, 0, stream>>>(hist, bbase);
    k_colscan<<<NBUCK, NBLK_E, 0, stream>>>(hist, bbase);
    k_bucket<<<NBLK_E, 512, 0, stream>>>(ei, hist, ebuf);

    float* pc  = pA;
    float* pnx = pB;
    for (int l = 0; l < 5; ++l) {
        if (l < 4)
            k_layer<1><<<NBUCK, 256, 0, stream>>>(pc, bbase, ebuf, b1[l], w2[l], b2[l],
                                                  w1[l + 1], h, pnx);
        else
            k_layer<0><<<NBUCK, 256, 0, stream>>>(pc, bbase, ebuf, b1[l], w2[l], b2[l],
                                                  nullptr, h, nullptr);
        k_pool<<<N_GRAPHS, 256, 0, stream>>>(h, gptr, pool + l * N_GRAPHS * DIM);
        float* tmp = pc; pc = pnx; pnx = tmp;
    }
    k_out<<<(N_GRAPHS * OUT + 255) / 256, 256, 0, stream>>>(
        pool, gptr, lp[0], lp[1], lp[2], lp[3], lp[4], out);
}

// Round 4
// 746.703 us; speedup vs baseline: 1.6952x; 1.6952x over previous
//
#include <hip/hip_runtime.h>
#include <math.h>

#define N_NODES  100000
#define N_EDGES  3200000
#define N_GRAPHS 512
#define N_FEAT   128
#define DIM      10
#define PDIM     12      // padded p-row stride (floats), 48B
#define OUT      16
#define NBLK     ((N_NODES + 255) / 256)

#define BW       128                         // nodes per bucket
#define BSHIFT   7
#define NBUCK    ((N_NODES + BW - 1) / BW)   // 782
#define NBLK_E   512                         // blocks in edge passes
#define EPB      ((N_EDGES + NBLK_E - 1) / NBLK_E)  // 6250
#define CAP      12288                       // LDS edge staging per bucket (48KB; ~3x expected max 4500)

// gptr[g] = first node with batch >= g (batch sorted). gptr[N_GRAPHS] = N_NODES.
__global__ void k_bounds(const int* __restrict__ batch, int* __restrict__ gptr) {
    int n = blockIdx.x * blockDim.x + threadIdx.x;
    if (n >= N_NODES) return;
    int bn = batch[n];
    int bp = (n == 0) ? -1 : batch[n - 1];
    for (int g = bp + 1; g <= bn; ++g) gptr[g] = n;
    if (n == N_NODES - 1)
        for (int g = bn + 1; g <= N_GRAPHS; ++g) gptr[g] = N_NODES;
}

// p[n][f] = sum_j x[n][j] * w1[j][f]  (128 -> 10), one wave per node
__global__ void k_proj1(const float* __restrict__ x, const float* __restrict__ w1,
                        float* __restrict__ p) {
    int wid  = (blockIdx.x * blockDim.x + threadIdx.x) >> 6;
    int lane = threadIdx.x & 63;
    if (wid >= N_NODES) return;
    float x1 = x[wid * N_FEAT + lane];
    float x2 = x[wid * N_FEAT + 64 + lane];
    float acc[DIM];
#pragma unroll
    for (int f = 0; f < DIM; ++f)
        acc[f] = x1 * w1[lane * DIM + f] + x2 * w1[(lane + 64) * DIM + f];
#pragma unroll
    for (int f = 0; f < DIM; ++f) {
        float v = acc[f];
        v += __shfl_xor(v, 32); v += __shfl_xor(v, 16); v += __shfl_xor(v, 8);
        v += __shfl_xor(v, 4);  v += __shfl_xor(v, 2);  v += __shfl_xor(v, 1);
        acc[f] = v;
    }
    if (lane == 0) {
#pragma unroll
        for (int f = 0; f < DIM; ++f) p[wid * PDIM + f] = acc[f];
    }
}

// ---- deterministic bucket sort of edges by dst>>BSHIFT (no global atomics) ----
__global__ void k_hist(const int* __restrict__ ei, int* __restrict__ hist) {
    __shared__ int s_h[NBUCK];
    for (int i = threadIdx.x; i < NBUCK; i += blockDim.x) s_h[i] = 0;
    __syncthreads();
    int base = blockIdx.x * EPB;
    int end  = min(base + EPB, N_EDGES);
    for (int e = base + threadIdx.x; e < end; e += blockDim.x)
        atomicAdd(&s_h[ei[N_EDGES + e] >> BSHIFT], 1);
    __syncthreads();
    for (int i = threadIdx.x; i < NBUCK; i += blockDim.x)
        hist[i * NBLK_E + blockIdx.x] = s_h[i];
}

// bbase[b] = total count of bucket b (one wave per bucket)
__global__ void k_btot(const int* __restrict__ hist, int* __restrict__ bbase) {
    int b = blockIdx.x, lane = threadIdx.x;
    int t = 0;
    for (int k = lane; k < NBLK_E; k += 64) t += hist[b * NBLK_E + k];
    t += __shfl_xor(t, 32); t += __shfl_xor(t, 16); t += __shfl_xor(t, 8);
    t += __shfl_xor(t, 4);  t += __shfl_xor(t, 2);  t += __shfl_xor(t, 1);
    if (lane == 0) bbase[b] = t;
}

// exclusive scan of bbase; bbase[NBUCK] = N_EDGES; rowp[N_NODES] = N_EDGES
__global__ void k_bscan(int* __restrict__ bbase, int* __restrict__ rowp) {
    __shared__ int s[1024];
    int tid = threadIdx.x;
    int v = (tid < NBUCK) ? bbase[tid] : 0;
    s[tid] = v;
    __syncthreads();
    for (int off = 1; off < 1024; off <<= 1) {
        int w = (tid >= off) ? s[tid - off] : 0;
        __syncthreads();
        s[tid] += w;
        __syncthreads();
    }
    if (tid < NBUCK) bbase[tid] = s[tid] - v;   // exclusive
    if (tid == 0) { bbase[NBUCK] = s[1023]; rowp[N_NODES] = s[1023]; }
}

// in-place: hist[b][blk] -> global base offset for (bucket b, block blk)
__global__ void k_colscan(int* __restrict__ hist, const int* __restrict__ bbase) {
    __shared__ int s[NBLK_E];
    int b = blockIdx.x, tid = threadIdx.x;
    int v = hist[b * NBLK_E + tid];
    s[tid] = v;
    __syncthreads();
    for (int off = 1; off < NBLK_E; off <<= 1) {
        int w = (tid >= off) ? s[tid - off] : 0;
        __syncthreads();
        s[tid] += w;
        __syncthreads();
    }
    hist[b * NBLK_E + tid] = bbase[b] + s[tid] - v;
}

// scatter edges bucket-grouped into col (packed (dst&127)<<17|src); LDS cursors only
__global__ void k_bucket(const int* __restrict__ ei, const int* __restrict__ off,
                         int* __restrict__ col) {
    __shared__ int loc[NBUCK];
    for (int i = threadIdx.x; i < NBUCK; i += blockDim.x)
        loc[i] = off[i * NBLK_E + blockIdx.x];
    __syncthreads();
    int base = blockIdx.x * EPB;
    int end  = min(base + EPB, N_EDGES);
    for (int e = base + threadIdx.x; e < end; e += blockDim.x) {
        int src = ei[e];
        int dst = ei[N_EDGES + e];
        int bkt = dst >> BSHIFT;
        int pos = atomicAdd(&loc[bkt], 1);         // LDS atomic
        col[pos] = ((dst & (BW - 1)) << 17) | src;
    }
}

// within-bucket counting sort: bucket range of col (packed) -> CSR order (plain src), writes rowp
__global__ void k_sort(const int* __restrict__ bbase, int* __restrict__ col,
                       int* __restrict__ rowp) {
    __shared__ int s_e[CAP];
    __shared__ int s_cnt[BW];
    __shared__ int s_scan[BW];
    __shared__ int s_cur[BW];
    int b = blockIdx.x, tid = threadIdx.x;
    int beg = bbase[b], end = bbase[b + 1], m = end - beg;
    for (int i = tid; i < m; i += 256) s_e[i] = col[beg + i];
    if (tid < BW) s_cnt[tid] = 0;
    __syncthreads();
    for (int i = tid; i < m; i += 256) atomicAdd(&s_cnt[s_e[i] >> 17], 1);
    __syncthreads();
    if (tid < BW) s_scan[tid] = s_cnt[tid];
    __syncthreads();
    for (int off = 1; off < BW; off <<= 1) {
        int v = (tid < BW && tid >= off) ? s_scan[tid - off] : 0;
        __syncthreads();
        if (tid < BW) s_scan[tid] += v;
        __syncthreads();
    }
    if (tid < BW) {
        int excl = s_scan[tid] - s_cnt[tid];
        s_cur[tid] = excl;
        int n = b * BW + tid;
        if (n < N_NODES) rowp[n] = beg + excl;
    }
    __syncthreads();
    for (int i = tid; i < m; i += 256) {
        int pk = s_e[i];
        int pos = atomicAdd(&s_cur[pk >> 17], 1);
        col[beg + pos] = pk & 0x1FFFF;
    }
}

// ---- fused layer: 16 lanes per node. gather+butterfly agg, MLP, pool-atomic, next proj ----
template <int HAS_NEXT>
__global__ void k_layer(const float* __restrict__ p, const int* __restrict__ rowp,
                        const int* __restrict__ col, const int* __restrict__ batch,
                        const float* __restrict__ b1, const float* __restrict__ w2,
                        const float* __restrict__ b2, const float* __restrict__ w1n,
                        float* __restrict__ poolL, float* __restrict__ pn) {
    __shared__ __align__(16) float s_w2[120], s_w1n[120];
    __shared__ float s_b1[DIM], s_b2[DIM];
    int tid = threadIdx.x;
    if (tid < 120) {
        int j = tid / 12, f = tid - j * 12;
        s_w2[tid] = (f < 10) ? w2[j * 10 + f] : 0.f;
        if (HAS_NEXT) s_w1n[tid] = (f < 10) ? w1n[j * 10 + f] : 0.f;
    }
    if (tid < DIM) { s_b1[tid] = b1[tid]; s_b2[tid] = b2[tid]; }
    __syncthreads();

    int n  = blockIdx.x * 16 + (tid >> 4);   // grid covers exactly N_NODES
    int sl = tid & 15;
    int beg = rowp[n], end = rowp[n + 1];

    float acc[DIM];
#pragma unroll
    for (int f = 0; f < DIM; ++f) acc[f] = 0.f;
    for (int j = beg + sl; j < end; j += 16) {
        int src = col[j];
        const float4* q = (const float4*)&p[src * PDIM];
        float4 a = q[0], b = q[1];
        float2 c = *(const float2*)&p[src * PDIM + 8];
        acc[0] += a.x; acc[1] += a.y; acc[2] += a.z; acc[3] += a.w;
        acc[4] += b.x; acc[5] += b.y; acc[6] += b.z; acc[7] += b.w;
        acc[8] += c.x; acc[9] += c.y;
    }
    // butterfly within 16-lane group (one instruction serves 4 nodes of the wave)
#pragma unroll
    for (int f = 0; f < DIM; ++f) {
        float v = acc[f];
        v += __shfl_xor(v, 8); v += __shfl_xor(v, 4);
        v += __shfl_xor(v, 2); v += __shfl_xor(v, 1);
        acc[f] = v;
    }
    // own row + bias + relu
    const float4* q = (const float4*)&p[n * PDIM];
    float4 oa = q[0], ob = q[1];
    float2 oc = *(const float2*)&p[n * PDIM + 8];
    float own[DIM] = {oa.x, oa.y, oa.z, oa.w, ob.x, ob.y, ob.z, ob.w, oc.x, oc.y};
    float u[DIM];
#pragma unroll
    for (int f = 0; f < DIM; ++f) u[f] = fmaxf(own[f] + acc[f] + s_b1[f], 0.f);
    // hv = relu(u @ w2 + b2)
    float hv[DIM];
#pragma unroll
    for (int f = 0; f < DIM; ++f) hv[f] = s_b2[f];
#pragma unroll
    for (int j = 0; j < DIM; ++j) {
        float uj = u[j];
        const float4* wr = (const float4*)&s_w2[j * 12];
        float4 wa = wr[0], wb = wr[1];
        float2 wc = *(const float2*)&s_w2[j * 12 + 8];
        hv[0] += uj * wa.x; hv[1] += uj * wa.y; hv[2] += uj * wa.z; hv[3] += uj * wa.w;
        hv[4] += uj * wb.x; hv[5] += uj * wb.y; hv[6] += uj * wb.z; hv[7] += uj * wb.w;
        hv[8] += uj * wc.x; hv[9] += uj * wc.y;
    }
#pragma unroll
    for (int f = 0; f < DIM; ++f) hv[f] = fmaxf(hv[f], 0.f);
    // fused mean-pool accumulation (sum; divide in k_out)
    if (sl < DIM) {
        float sel = hv[0];
#pragma unroll
        for (int f = 1; f < DIM; ++f) sel = (sl == f) ? hv[f] : sel;
        atomicAdd(&poolL[batch[n] * DIM + sl], sel);
    }
    if (HAS_NEXT) {
        float pv[DIM];
#pragma unroll
        for (int f = 0; f < DIM; ++f) pv[f] = 0.f;
#pragma unroll
        for (int j = 0; j < DIM; ++j) {
            float hj = hv[j];
            const float4* wr = (const float4*)&s_w1n[j * 12];
            float4 wa = wr[0], wb = wr[1];
            float2 wc = *(const float2*)&s_w1n[j * 12 + 8];
            pv[0] += hj * wa.x; pv[1] += hj * wa.y; pv[2] += hj * wa.z; pv[3] += hj * wa.w;
            pv[4] += hj * wb.x; pv[5] += hj * wb.y; pv[6] += hj * wb.z; pv[7] += hj * wb.w;
            pv[8] += hj * wc.x; pv[9] += hj * wc.y;
        }
        if (sl < DIM) {
            float sel = pv[0];
#pragma unroll
            for (int f = 1; f < DIM; ++f) sel = (sl == f) ? pv[f] : sel;
            pn[n * PDIM + sl] = sel;
        }
    }
}

__global__ void k_out(const float* __restrict__ pool, const int* __restrict__ gptr,
                      const float* __restrict__ l1, const float* __restrict__ l2,
                      const float* __restrict__ l3, const float* __restrict__ l4,
                      const float* __restrict__ l5, float* __restrict__ out) {
    int t = blockIdx.x * blockDim.x + threadIdx.x;
    if (t >= N_GRAPHS * OUT) return;
    int g = t >> 4;
    int o = t & 15;
    float cnt = fmaxf((float)(gptr[g + 1] - gptr[g]), 1.f);
    const float* ls[5] = {l1, l2, l3, l4, l5};
    float acc = 0.f;
#pragma unroll
    for (int l = 0; l < 5; ++l)
#pragma unroll
        for (int f = 0; f < DIM; ++f)
            acc += pool[(l * N_GRAPHS + g) * DIM + f] * ls[l][f * OUT + o];
    out[t] = tanhf(acc / cnt);
}

extern "C" void kernel_launch(void* const* d_in, const int* in_sizes, int n_in,
                              void* d_out, int out_size, void* d_ws, size_t ws_size,
                              hipStream_t stream) {
    const float* x     = (const float*)d_in[0];
    const int*   ei    = (const int*)d_in[1];
    const int*   batch = (const int*)d_in[2];
    const float *w1[5], *b1[5], *w2[5], *b2[5], *lp[5];
    for (int l = 0; l < 5; ++l) {
        w1[l] = (const float*)d_in[3 + l * 4 + 0];
        b1[l] = (const float*)d_in[3 + l * 4 + 1];
        w2[l] = (const float*)d_in[3 + l * 4 + 2];
        b2[l] = (const float*)d_in[3 + l * 4 + 3];
        lp[l] = (const float*)d_in[23 + l];
    }
    float* out = (float*)d_out;

    // workspace (~24.5 MB)
    float* pA    = (float*)d_ws;                        // 1,200,000 floats
    float* pB    = pA + N_NODES * PDIM;                 // 1,200,000
    float* pool  = pB + N_NODES * PDIM;                 // 25,600
    int*   gptr  = (int*)(pool + 5 * N_GRAPHS * DIM);   // 513 -> pad 516
    int*   bbase = gptr + 516;                          // NBUCK+1 -> pad 784
    int*   rowp  = bbase + 784;                         // 100,001 -> pad 100,004
    int*   col   = rowp + 100004;                       // N_EDGES (packed, then CSR col)
    int*   hist  = col + N_EDGES;                       // NBUCK*NBLK_E = 400,384

    hipMemsetAsync(pool, 0, 5 * N_GRAPHS * DIM * sizeof(float), stream);

    k_bounds<<<NBLK, 256, 0, stream>>>(batch, gptr);
    k_proj1<<<(N_NODES * 64 + 255) / 256, 256, 0, stream>>>(x, w1[0], pA);

    // deterministic CSR build: bucket by dst>>7, then counting-sort within bucket
    k_hist<<<NBLK_E, 512, 0, stream>>>(ei, hist);
    k_btot<<<NBUCK, 64, 0, stream>>>(hist, bbase);
    k_bscan<<<1, 1024, 0, stream>>>(bbase, rowp);
    k_colscan<<<NBUCK, NBLK_E, 0, stream>>>(hist, bbase);
    k_bucket<<<NBLK_E, 512, 0, stream>>>(ei, hist, col);
    k_sort<<<NBUCK, 256, 0, stream>>>(bbase, col, rowp);

    float* pc  = pA;
    float* pnx = pB;
    for (int l = 0; l < 5; ++l) {
        float* poolL = pool + l * N_GRAPHS * DIM;
        if (l < 4)
            k_layer<1><<<N_NODES / 16, 256, 0, stream>>>(pc, rowp, col, batch,
                b1[l], w2[l], b2[l], w1[l + 1], poolL, pnx);
        else
            k_layer<0><<<N_NODES / 16, 256, 0, stream>>>(pc, rowp, col, batch,
                b1[l], w2[l], b2[l], nullptr, poolL, nullptr);
        float* tmp = pc; pc = pnx; pnx = tmp;
    }
    k_out<<<(N_GRAPHS * OUT + 255) / 256, 256, 0, stream>>>(
        pool, gptr, lp[0], lp[1], lp[2], lp[3], lp[4], out);
}

// Round 5
// 643.051 us; speedup vs baseline: 1.9684x; 1.1612x over previous
//
#include <hip/hip_runtime.h>
#include <hip/hip_fp16.h>
#include <math.h>

#define N_NODES  100000
#define N_EDGES  3200000
#define N_GRAPHS 512
#define N_FEAT   128
#define DIM      10
#define PH       16      // fp16 row stride (halves) = 32B, row 32B-aligned
#define OUT      16
#define NBLK     ((N_NODES + 255) / 256)

#define BW       128                         // nodes per bucket
#define BSHIFT   7
#define NBUCK    ((N_NODES + BW - 1) / BW)   // 782
#define NBLK_E   512                         // blocks in edge passes
#define EPB      ((N_EDGES + NBLK_E - 1) / NBLK_E)  // 6250
#define CAP      12288                       // LDS edge staging per bucket

// gptr[g] = first node with batch >= g (batch sorted). gptr[N_GRAPHS] = N_NODES.
__global__ void k_bounds(const int* __restrict__ batch, int* __restrict__ gptr) {
    int n = blockIdx.x * blockDim.x + threadIdx.x;
    if (n >= N_NODES) return;
    int bn = batch[n];
    int bp = (n == 0) ? -1 : batch[n - 1];
    for (int g = bp + 1; g <= bn; ++g) gptr[g] = n;
    if (n == N_NODES - 1)
        for (int g = bn + 1; g <= N_GRAPHS; ++g) gptr[g] = N_NODES;
}

// p[n][f] = sum_j x[n][j] * w1[j][f]  (128 -> 10), one wave per node; fp16 packed out
__global__ void k_proj1(const float* __restrict__ x, const float* __restrict__ w1,
                        ushort* __restrict__ pt) {
    int wid  = (blockIdx.x * blockDim.x + threadIdx.x) >> 6;
    int lane = threadIdx.x & 63;
    if (wid >= N_NODES) return;
    float x1 = x[wid * N_FEAT + lane];
    float x2 = x[wid * N_FEAT + 64 + lane];
    float acc[DIM];
#pragma unroll
    for (int f = 0; f < DIM; ++f)
        acc[f] = x1 * w1[lane * DIM + f] + x2 * w1[(lane + 64) * DIM + f];
#pragma unroll
    for (int f = 0; f < DIM; ++f) {
        float v = acc[f];
        v += __shfl_xor(v, 32); v += __shfl_xor(v, 16); v += __shfl_xor(v, 8);
        v += __shfl_xor(v, 4);  v += __shfl_xor(v, 2);  v += __shfl_xor(v, 1);
        acc[f] = v;
    }
    if (lane == 0) {
        union { __half2 h; unsigned u; } c0, c1, c2, c3, c4;
        c0.h = __floats2half2_rn(acc[0], acc[1]);
        c1.h = __floats2half2_rn(acc[2], acc[3]);
        c2.h = __floats2half2_rn(acc[4], acc[5]);
        c3.h = __floats2half2_rn(acc[6], acc[7]);
        c4.h = __floats2half2_rn(acc[8], acc[9]);
        uint4 s; s.x = c0.u; s.y = c1.u; s.z = c2.u; s.w = c3.u;
        *(uint4*)&pt[wid * PH] = s;
        *(unsigned*)&pt[wid * PH + 8] = c4.u;
    }
}

// ---- deterministic bucket sort of edges by dst>>BSHIFT (no global atomics) ----
__global__ void k_hist(const int* __restrict__ ei, int* __restrict__ hist) {
    __shared__ int s_h[NBUCK];
    for (int i = threadIdx.x; i < NBUCK; i += blockDim.x) s_h[i] = 0;
    __syncthreads();
    int base = blockIdx.x * EPB;
    int end  = min(base + EPB, N_EDGES);
    for (int e = base + threadIdx.x; e < end; e += blockDim.x)
        atomicAdd(&s_h[ei[N_EDGES + e] >> BSHIFT], 1);
    __syncthreads();
    for (int i = threadIdx.x; i < NBUCK; i += blockDim.x)
        hist[i * NBLK_E + blockIdx.x] = s_h[i];
}

__global__ void k_btot(const int* __restrict__ hist, int* __restrict__ bbase) {
    int b = blockIdx.x, lane = threadIdx.x;
    int t = 0;
    for (int k = lane; k < NBLK_E; k += 64) t += hist[b * NBLK_E + k];
    t += __shfl_xor(t, 32); t += __shfl_xor(t, 16); t += __shfl_xor(t, 8);
    t += __shfl_xor(t, 4);  t += __shfl_xor(t, 2);  t += __shfl_xor(t, 1);
    if (lane == 0) bbase[b] = t;
}

__global__ void k_bscan(int* __restrict__ bbase, int* __restrict__ rowp) {
    __shared__ int s[1024];
    int tid = threadIdx.x;
    int v = (tid < NBUCK) ? bbase[tid] : 0;
    s[tid] = v;
    __syncthreads();
    for (int off = 1; off < 1024; off <<= 1) {
        int w = (tid >= off) ? s[tid - off] : 0;
        __syncthreads();
        s[tid] += w;
        __syncthreads();
    }
    if (tid < NBUCK) bbase[tid] = s[tid] - v;
    if (tid == 0) { bbase[NBUCK] = s[1023]; rowp[N_NODES] = s[1023]; }
}

__global__ void k_colscan(int* __restrict__ hist, const int* __restrict__ bbase) {
    __shared__ int s[NBLK_E];
    int b = blockIdx.x, tid = threadIdx.x;
    int v = hist[b * NBLK_E + tid];
    s[tid] = v;
    __syncthreads();
    for (int off = 1; off < NBLK_E; off <<= 1) {
        int w = (tid >= off) ? s[tid - off] : 0;
        __syncthreads();
        s[tid] += w;
        __syncthreads();
    }
    hist[b * NBLK_E + tid] = bbase[b] + s[tid] - v;
}

__global__ void k_bucket(const int* __restrict__ ei, const int* __restrict__ off,
                         int* __restrict__ col) {
    __shared__ int loc[NBUCK];
    for (int i = threadIdx.x; i < NBUCK; i += blockDim.x)
        loc[i] = off[i * NBLK_E + blockIdx.x];
    __syncthreads();
    int base = blockIdx.x * EPB;
    int end  = min(base + EPB, N_EDGES);
    for (int e = base + threadIdx.x; e < end; e += blockDim.x) {
        int src = ei[e];
        int dst = ei[N_EDGES + e];
        int bkt = dst >> BSHIFT;
        int pos = atomicAdd(&loc[bkt], 1);         // LDS atomic
        col[pos] = ((dst & (BW - 1)) << 17) | src;
    }
}

__global__ void k_sort(const int* __restrict__ bbase, int* __restrict__ col,
                       int* __restrict__ rowp) {
    __shared__ int s_e[CAP];
    __shared__ int s_cnt[BW];
    __shared__ int s_scan[BW];
    __shared__ int s_cur[BW];
    int b = blockIdx.x, tid = threadIdx.x;
    int beg = bbase[b], end = bbase[b + 1], m = end - beg;
    for (int i = tid; i < m; i += 256) s_e[i] = col[beg + i];
    if (tid < BW) s_cnt[tid] = 0;
    __syncthreads();
    for (int i = tid; i < m; i += 256) atomicAdd(&s_cnt[s_e[i] >> 17], 1);
    __syncthreads();
    if (tid < BW) s_scan[tid] = s_cnt[tid];
    __syncthreads();
    for (int off = 1; off < BW; off <<= 1) {
        int v = (tid < BW && tid >= off) ? s_scan[tid - off] : 0;
        __syncthreads();
        if (tid < BW) s_scan[tid] += v;
        __syncthreads();
    }
    if (tid < BW) {
        int excl = s_scan[tid] - s_cnt[tid];
        s_cur[tid] = excl;
        int n = b * BW + tid;
        if (n < N_NODES) rowp[n] = beg + excl;
    }
    __syncthreads();
    for (int i = tid; i < m; i += 256) {
        int pk = s_e[i];
        int pos = atomicAdd(&s_cur[pk >> 17], 1);
        col[beg + pos] = pk & 0x1FFFF;
    }
}

// ---- fused layer: 32 lanes per node; fp16 one-line gathers, fp32 math ----
template <int HAS_NEXT>
__global__ void k_layer(const ushort* __restrict__ pt, const int* __restrict__ rowp,
                        const int* __restrict__ col, const int* __restrict__ batch,
                        const float* __restrict__ b1, const float* __restrict__ w2,
                        const float* __restrict__ b2, const float* __restrict__ w1n,
                        float* __restrict__ poolL, ushort* __restrict__ pn) {
    __shared__ __align__(16) float s_w2[120], s_w1n[120];
    __shared__ float s_b1[DIM], s_b2[DIM];
    int tid = threadIdx.x;
    if (tid < 120) {
        int j = tid / 12, f = tid - j * 12;
        s_w2[tid] = (f < 10) ? w2[j * 10 + f] : 0.f;
        if (HAS_NEXT) s_w1n[tid] = (f < 10) ? w1n[j * 10 + f] : 0.f;
    }
    if (tid < DIM) { s_b1[tid] = b1[tid]; s_b2[tid] = b2[tid]; }
    __syncthreads();

    int n  = blockIdx.x * 8 + (tid >> 5);   // 8 nodes/block, grid covers N exactly
    int sl = tid & 31;
    int beg = rowp[n], end = rowp[n + 1];

    float acc[DIM];
#pragma unroll
    for (int f = 0; f < DIM; ++f) acc[f] = 0.f;
    for (int j = beg + sl; j < end; j += 32) {
        int src = __builtin_nontemporal_load(&col[j]);
        uint4 a = *(const uint4*)&pt[src * PH];           // halves 0..7, one 64B line
        unsigned b = *(const unsigned*)&pt[src * PH + 8]; // halves 8,9 (same line)
        float2 f0 = __half22float2(*(__half2*)&a.x);
        float2 f1 = __half22float2(*(__half2*)&a.y);
        float2 f2 = __half22float2(*(__half2*)&a.z);
        float2 f3 = __half22float2(*(__half2*)&a.w);
        float2 f4 = __half22float2(*(__half2*)&b);
        acc[0] += f0.x; acc[1] += f0.y; acc[2] += f1.x; acc[3] += f1.y;
        acc[4] += f2.x; acc[5] += f2.y; acc[6] += f3.x; acc[7] += f3.y;
        acc[8] += f4.x; acc[9] += f4.y;
    }
    // butterfly within 32-lane group
#pragma unroll
    for (int f = 0; f < DIM; ++f) {
        float v = acc[f];
        v += __shfl_xor(v, 16); v += __shfl_xor(v, 8);
        v += __shfl_xor(v, 4);  v += __shfl_xor(v, 2); v += __shfl_xor(v, 1);
        acc[f] = v;
    }
    // own row + bias + relu (fp16 storage, fp32 math)
    float own[DIM];
    {
        uint4 a = *(const uint4*)&pt[n * PH];
        unsigned b = *(const unsigned*)&pt[n * PH + 8];
        float2 f0 = __half22float2(*(__half2*)&a.x);
        float2 f1 = __half22float2(*(__half2*)&a.y);
        float2 f2 = __half22float2(*(__half2*)&a.z);
        float2 f3 = __half22float2(*(__half2*)&a.w);
        float2 f4 = __half22float2(*(__half2*)&b);
        own[0] = f0.x; own[1] = f0.y; own[2] = f1.x; own[3] = f1.y;
        own[4] = f2.x; own[5] = f2.y; own[6] = f3.x; own[7] = f3.y;
        own[8] = f4.x; own[9] = f4.y;
    }
    float u[DIM];
#pragma unroll
    for (int f = 0; f < DIM; ++f) u[f] = fmaxf(own[f] + acc[f] + s_b1[f], 0.f);
    float hv[DIM];
#pragma unroll
    for (int f = 0; f < DIM; ++f) hv[f] = s_b2[f];
#pragma unroll
    for (int j = 0; j < DIM; ++j) {
        float uj = u[j];
        const float4* wr = (const float4*)&s_w2[j * 12];
        float4 wa = wr[0], wb = wr[1];
        float2 wc = *(const float2*)&s_w2[j * 12 + 8];
        hv[0] += uj * wa.x; hv[1] += uj * wa.y; hv[2] += uj * wa.z; hv[3] += uj * wa.w;
        hv[4] += uj * wb.x; hv[5] += uj * wb.y; hv[6] += uj * wb.z; hv[7] += uj * wb.w;
        hv[8] += uj * wc.x; hv[9] += uj * wc.y;
    }
#pragma unroll
    for (int f = 0; f < DIM; ++f) hv[f] = fmaxf(hv[f], 0.f);
    // fused mean-pool accumulation (sum; divide in k_out)
    if (sl < DIM) {
        float sel = hv[0];
#pragma unroll
        for (int f = 1; f < DIM; ++f) sel = (sl == f) ? hv[f] : sel;
        atomicAdd(&poolL[batch[n] * DIM + sl], sel);
    }
    if (HAS_NEXT) {
        float pv[DIM];
#pragma unroll
        for (int f = 0; f < DIM; ++f) pv[f] = 0.f;
#pragma unroll
        for (int j = 0; j < DIM; ++j) {
            float hj = hv[j];
            const float4* wr = (const float4*)&s_w1n[j * 12];
            float4 wa = wr[0], wb = wr[1];
            float2 wc = *(const float2*)&s_w1n[j * 12 + 8];
            pv[0] += hj * wa.x; pv[1] += hj * wa.y; pv[2] += hj * wa.z; pv[3] += hj * wa.w;
            pv[4] += hj * wb.x; pv[5] += hj * wb.y; pv[6] += hj * wb.z; pv[7] += hj * wb.w;
            pv[8] += hj * wc.x; pv[9] += hj * wc.y;
        }
        if (sl == 0) {   // all static indices; one lane stores the packed row
            union { __half2 h; unsigned u; } c0, c1, c2, c3, c4;
            c0.h = __floats2half2_rn(pv[0], pv[1]);
            c1.h = __floats2half2_rn(pv[2], pv[3]);
            c2.h = __floats2half2_rn(pv[4], pv[5]);
            c3.h = __floats2half2_rn(pv[6], pv[7]);
            c4.h = __floats2half2_rn(pv[8], pv[9]);
            uint4 s; s.x = c0.u; s.y = c1.u; s.z = c2.u; s.w = c3.u;
            *(uint4*)&pn[n * PH] = s;
            *(unsigned*)&pn[n * PH + 8] = c4.u;
        }
    }
}

__global__ void k_out(const float* __restrict__ pool, const int* __restrict__ gptr,
                      const float* __restrict__ l1, const float* __restrict__ l2,
                      const float* __restrict__ l3, const float* __restrict__ l4,
                      const float* __restrict__ l5, float* __restrict__ out) {
    int t = blockIdx.x * blockDim.x + threadIdx.x;
    if (t >= N_GRAPHS * OUT) return;
    int g = t >> 4;
    int o = t & 15;
    float cnt = fmaxf((float)(gptr[g + 1] - gptr[g]), 1.f);
    const float* ls[5] = {l1, l2, l3, l4, l5};
    float acc = 0.f;
#pragma unroll
    for (int l = 0; l < 5; ++l)
#pragma unroll
        for (int f = 0; f < DIM; ++f)
            acc += pool[(l * N_GRAPHS + g) * DIM + f] * ls[l][f * OUT + o];
    out[t] = tanhf(acc / cnt);
}

extern "C" void kernel_launch(void* const* d_in, const int* in_sizes, int n_in,
                              void* d_out, int out_size, void* d_ws, size_t ws_size,
                              hipStream_t stream) {
    const float* x     = (const float*)d_in[0];
    const int*   ei    = (const int*)d_in[1];
    const int*   batch = (const int*)d_in[2];
    const float *w1[5], *b1[5], *w2[5], *b2[5], *lp[5];
    for (int l = 0; l < 5; ++l) {
        w1[l] = (const float*)d_in[3 + l * 4 + 0];
        b1[l] = (const float*)d_in[3 + l * 4 + 1];
        w2[l] = (const float*)d_in[3 + l * 4 + 2];
        b2[l] = (const float*)d_in[3 + l * 4 + 3];
        lp[l] = (const float*)d_in[23 + l];
    }
    float* out = (float*)d_out;

    // workspace (~21.3 MB)
    ushort* ptA  = (ushort*)d_ws;                       // N*PH = 1.6M ushorts (3.2MB)
    ushort* ptB  = ptA + N_NODES * PH;                  // 3.2MB
    float*  pool = (float*)(ptB + N_NODES * PH);        // 25,600 floats
    int*    gptr = (int*)(pool + 5 * N_GRAPHS * DIM);   // 513 -> pad 516
    int*    bbase= gptr + 516;                          // NBUCK+1 -> pad 784
    int*    rowp = bbase + 784;                         // 100,001 -> pad 100,004
    int*    col  = rowp + 100004;                       // N_EDGES
    int*    hist = col + N_EDGES;                       // NBUCK*NBLK_E

    hipMemsetAsync(pool, 0, 5 * N_GRAPHS * DIM * sizeof(float), stream);

    k_bounds<<<NBLK, 256, 0, stream>>>(batch, gptr);
    k_proj1<<<(N_NODES * 64 + 255) / 256, 256, 0, stream>>>(x, w1[0], ptA);

    k_hist<<<NBLK_E, 512, 0, stream>>>(ei, hist);
    k_btot<<<NBUCK, 64, 0, stream>>>(hist, bbase);
    k_bscan<<<1, 1024, 0, stream>>>(bbase, rowp);
    k_colscan<<<NBUCK, NBLK_E, 0, stream>>>(hist, bbase);
    k_bucket<<<NBLK_E, 512, 0, stream>>>(ei, hist, col);
    k_sort<<<NBUCK, 256, 0, stream>>>(bbase, col, rowp);

    ushort* pc  = ptA;
    ushort* pnx = ptB;
    for (int l = 0; l < 5; ++l) {
        float* poolL = pool + l * N_GRAPHS * DIM;
        if (l < 4)
            k_layer<1><<<N_NODES / 8, 256, 0, stream>>>(pc, rowp, col, batch,
                b1[l], w2[l], b2[l], w1[l + 1], poolL, pnx);
        else
            k_layer<0><<<N_NODES / 8, 256, 0, stream>>>(pc, rowp, col, batch,
                b1[l], w2[l], b2[l], nullptr, poolL, nullptr);
        ushort* tmp = pc; pc = pnx; pnx = tmp;
    }
    k_out<<<(N_GRAPHS * OUT + 255) / 256, 256, 0, stream>>>(
        pool, gptr, lp[0], lp[1], lp[2], lp[3], lp[4], out);
}

// Round 6
// 618.890 us; speedup vs baseline: 2.0453x; 1.0390x over previous
//
#include <hip/hip_runtime.h>
#include <hip/hip_fp16.h>
#include <math.h>

#define N_NODES  100000
#define N_EDGES  3200000
#define N_GRAPHS 512
#define N_FEAT   128
#define DIM      10
#define PH       16      // fp16 row stride (halves) = 32B, row 32B-aligned
#define ZP       12      // fp32 z row stride (floats) = 48B
#define OUT      16
#define NBLK     ((N_NODES + 255) / 256)

#define BW       128                         // nodes per bucket
#define BSHIFT   7
#define NBUCK    ((N_NODES + BW - 1) / BW)   // 782
#define NBLK_E   512                         // blocks in edge passes
#define EPB      ((N_EDGES + NBLK_E - 1) / NBLK_E)  // 6250
#define CAP      12288                       // LDS edge staging per bucket

// gptr[g] = first node with batch >= g (batch sorted). gptr[N_GRAPHS] = N_NODES.
__global__ void k_bounds(const int* __restrict__ batch, int* __restrict__ gptr) {
    int n = blockIdx.x * blockDim.x + threadIdx.x;
    if (n >= N_NODES) return;
    int bn = batch[n];
    int bp = (n == 0) ? -1 : batch[n - 1];
    for (int g = bp + 1; g <= bn; ++g) gptr[g] = n;
    if (n == N_NODES - 1)
        for (int g = bn + 1; g <= N_GRAPHS; ++g) gptr[g] = N_NODES;
}

// p[n][f] = sum_j x[n][j] * w1[j][f]  (128 -> 10), one wave per node; fp16 packed out
__global__ void k_proj1(const float* __restrict__ x, const float* __restrict__ w1,
                        ushort* __restrict__ pt) {
    int wid  = (blockIdx.x * blockDim.x + threadIdx.x) >> 6;
    int lane = threadIdx.x & 63;
    if (wid >= N_NODES) return;
    float x1 = x[wid * N_FEAT + lane];
    float x2 = x[wid * N_FEAT + 64 + lane];
    float acc[DIM];
#pragma unroll
    for (int f = 0; f < DIM; ++f)
        acc[f] = x1 * w1[lane * DIM + f] + x2 * w1[(lane + 64) * DIM + f];
#pragma unroll
    for (int f = 0; f < DIM; ++f) {
        float v = acc[f];
        v += __shfl_xor(v, 32); v += __shfl_xor(v, 16); v += __shfl_xor(v, 8);
        v += __shfl_xor(v, 4);  v += __shfl_xor(v, 2);  v += __shfl_xor(v, 1);
        acc[f] = v;
    }
    if (lane == 0) {
        union { __half2 h; unsigned u; } c0, c1, c2, c3, c4;
        c0.h = __floats2half2_rn(acc[0], acc[1]);
        c1.h = __floats2half2_rn(acc[2], acc[3]);
        c2.h = __floats2half2_rn(acc[4], acc[5]);
        c3.h = __floats2half2_rn(acc[6], acc[7]);
        c4.h = __floats2half2_rn(acc[8], acc[9]);
        uint4 s; s.x = c0.u; s.y = c1.u; s.z = c2.u; s.w = c3.u;
        *(uint4*)&pt[wid * PH] = s;
        *(unsigned*)&pt[wid * PH + 8] = c4.u;
    }
}

// ---- deterministic bucket sort of edges by dst>>BSHIFT (no global atomics) ----
__global__ void k_hist(const int* __restrict__ ei, int* __restrict__ hist) {
    __shared__ int s_h[NBUCK];
    for (int i = threadIdx.x; i < NBUCK; i += blockDim.x) s_h[i] = 0;
    __syncthreads();
    int base = blockIdx.x * EPB;
    int end  = min(base + EPB, N_EDGES);
    for (int e = base + threadIdx.x; e < end; e += blockDim.x)
        atomicAdd(&s_h[ei[N_EDGES + e] >> BSHIFT], 1);
    __syncthreads();
    for (int i = threadIdx.x; i < NBUCK; i += blockDim.x)
        hist[i * NBLK_E + blockIdx.x] = s_h[i];
}

__global__ void k_btot(const int* __restrict__ hist, int* __restrict__ bbase) {
    int b = blockIdx.x, lane = threadIdx.x;
    int t = 0;
    for (int k = lane; k < NBLK_E; k += 64) t += hist[b * NBLK_E + k];
    t += __shfl_xor(t, 32); t += __shfl_xor(t, 16); t += __shfl_xor(t, 8);
    t += __shfl_xor(t, 4);  t += __shfl_xor(t, 2);  t += __shfl_xor(t, 1);
    if (lane == 0) bbase[b] = t;
}

__global__ void k_bscan(int* __restrict__ bbase, int* __restrict__ rowp) {
    __shared__ int s[1024];
    int tid = threadIdx.x;
    int v = (tid < NBUCK) ? bbase[tid] : 0;
    s[tid] = v;
    __syncthreads();
    for (int off = 1; off < 1024; off <<= 1) {
        int w = (tid >= off) ? s[tid - off] : 0;
        __syncthreads();
        s[tid] += w;
        __syncthreads();
    }
    if (tid < NBUCK) bbase[tid] = s[tid] - v;
    if (tid == 0) { bbase[NBUCK] = s[1023]; rowp[N_NODES] = s[1023]; }
}

__global__ void k_colscan(int* __restrict__ hist, const int* __restrict__ bbase) {
    __shared__ int s[NBLK_E];
    int b = blockIdx.x, tid = threadIdx.x;
    int v = hist[b * NBLK_E + tid];
    s[tid] = v;
    __syncthreads();
    for (int off = 1; off < NBLK_E; off <<= 1) {
        int w = (tid >= off) ? s[tid - off] : 0;
        __syncthreads();
        s[tid] += w;
        __syncthreads();
    }
    hist[b * NBLK_E + tid] = bbase[b] + s[tid] - v;
}

__global__ void k_bucket(const int* __restrict__ ei, const int* __restrict__ off,
                         int* __restrict__ col) {
    __shared__ int loc[NBUCK];
    for (int i = threadIdx.x; i < NBUCK; i += blockDim.x)
        loc[i] = off[i * NBLK_E + blockIdx.x];
    __syncthreads();
    int base = blockIdx.x * EPB;
    int end  = min(base + EPB, N_EDGES);
    for (int e = base + threadIdx.x; e < end; e += blockDim.x) {
        int src = ei[e];
        int dst = ei[N_EDGES + e];
        int bkt = dst >> BSHIFT;
        int pos = atomicAdd(&loc[bkt], 1);         // LDS atomic
        col[pos] = ((dst & (BW - 1)) << 17) | src;
    }
}

__global__ void k_sort(const int* __restrict__ bbase, int* __restrict__ col,
                       int* __restrict__ rowp) {
    __shared__ int s_e[CAP];
    __shared__ int s_cnt[BW];
    __shared__ int s_scan[BW];
    __shared__ int s_cur[BW];
    int b = blockIdx.x, tid = threadIdx.x;
    int beg = bbase[b], end = bbase[b + 1], m = end - beg;
    for (int i = tid; i < m; i += 256) s_e[i] = col[beg + i];
    if (tid < BW) s_cnt[tid] = 0;
    __syncthreads();
    for (int i = tid; i < m; i += 256) atomicAdd(&s_cnt[s_e[i] >> 17], 1);
    __syncthreads();
    if (tid < BW) s_scan[tid] = s_cnt[tid];
    __syncthreads();
    for (int off = 1; off < BW; off <<= 1) {
        int v = (tid < BW && tid >= off) ? s_scan[tid - off] : 0;
        __syncthreads();
        if (tid < BW) s_scan[tid] += v;
        __syncthreads();
    }
    if (tid < BW) {
        int excl = s_scan[tid] - s_cnt[tid];
        s_cur[tid] = excl;
        int n = b * BW + tid;
        if (n < N_NODES) rowp[n] = beg + excl;
    }
    __syncthreads();
    for (int i = tid; i < m; i += 256) {
        int pk = s_e[i];
        int pos = atomicAdd(&s_cur[pk >> 17], 1);
        col[beg + pos] = pk & 0x1FFFF;
    }
}

// ---- aggregation: 4 lanes/node; z[n] = p[n] + sum_{src->n} p[src] (fp32 out) ----
__global__ void k_agg(const ushort* __restrict__ pt, const int* __restrict__ rowp,
                      const int* __restrict__ col, float* __restrict__ z) {
    int t = blockIdx.x * blockDim.x + threadIdx.x;
    int n = t >> 2, sl = t & 3;
    if (n >= N_NODES) return;          // whole 4-group exits together
    int beg = rowp[n], end = rowp[n + 1];
    float acc[DIM] = {0.f,0.f,0.f,0.f,0.f,0.f,0.f,0.f,0.f,0.f};
    for (int j = beg + sl; j < end; j += 4) {
        int src = __builtin_nontemporal_load(&col[j]);
        uint4 a = *(const uint4*)&pt[src * PH];
        unsigned b = *(const unsigned*)&pt[src * PH + 8];
        float2 f0 = __half22float2(*(__half2*)&a.x);
        float2 f1 = __half22float2(*(__half2*)&a.y);
        float2 f2 = __half22float2(*(__half2*)&a.z);
        float2 f3 = __half22float2(*(__half2*)&a.w);
        float2 f4 = __half22float2(*(__half2*)&b);
        acc[0] += f0.x; acc[1] += f0.y; acc[2] += f1.x; acc[3] += f1.y;
        acc[4] += f2.x; acc[5] += f2.y; acc[6] += f3.x; acc[7] += f3.y;
        acc[8] += f4.x; acc[9] += f4.y;
    }
#pragma unroll
    for (int f = 0; f < DIM; ++f) {
        float v = acc[f];
        v += __shfl_xor(v, 1);
        v += __shfl_xor(v, 2);
        acc[f] = v;
    }
    if (sl == 0) {
        uint4 a = *(const uint4*)&pt[n * PH];
        unsigned b = *(const unsigned*)&pt[n * PH + 8];
        float2 f0 = __half22float2(*(__half2*)&a.x);
        float2 f1 = __half22float2(*(__half2*)&a.y);
        float2 f2 = __half22float2(*(__half2*)&a.z);
        float2 f3 = __half22float2(*(__half2*)&a.w);
        float2 f4 = __half22float2(*(__half2*)&b);
        float4 z0 = make_float4(acc[0] + f0.x, acc[1] + f0.y, acc[2] + f1.x, acc[3] + f1.y);
        float4 z1 = make_float4(acc[4] + f2.x, acc[5] + f2.y, acc[6] + f3.x, acc[7] + f3.y);
        float2 z2 = make_float2(acc[8] + f4.x, acc[9] + f4.y);
        *(float4*)&z[n * ZP]     = z0;
        *(float4*)&z[n * ZP + 4] = z1;
        *(float2*)&z[n * ZP + 8] = z2;
    }
}

// ---- node-parallel MLP + fused pool + next-layer projection ----
template <int HAS_NEXT>
__global__ void k_mlp(const float* __restrict__ z, const int* __restrict__ batch,
                      const float* __restrict__ b1, const float* __restrict__ w2,
                      const float* __restrict__ b2, const float* __restrict__ w1n,
                      float* __restrict__ poolL, ushort* __restrict__ pn) {
    __shared__ __align__(16) float s_w2[120], s_w1n[120];
    __shared__ float s_b1[DIM], s_b2[DIM];
    int tid = threadIdx.x;
    if (tid < 120) {
        int j = tid / 12, f = tid - j * 12;
        s_w2[tid] = (f < 10) ? w2[j * 10 + f] : 0.f;
        if (HAS_NEXT) s_w1n[tid] = (f < 10) ? w1n[j * 10 + f] : 0.f;
    }
    if (tid < DIM) { s_b1[tid] = b1[tid]; s_b2[tid] = b2[tid]; }
    __syncthreads();

    int n = blockIdx.x * blockDim.x + tid;
    bool valid = n < N_NODES;
    int nn = valid ? n : N_NODES - 1;
    int g = batch[nn];

    float u[DIM];
    if (valid) {
        float4 z0 = *(const float4*)&z[n * ZP];
        float4 z1 = *(const float4*)&z[n * ZP + 4];
        float2 z2 = *(const float2*)&z[n * ZP + 8];
        u[0] = fmaxf(z0.x + s_b1[0], 0.f); u[1] = fmaxf(z0.y + s_b1[1], 0.f);
        u[2] = fmaxf(z0.z + s_b1[2], 0.f); u[3] = fmaxf(z0.w + s_b1[3], 0.f);
        u[4] = fmaxf(z1.x + s_b1[4], 0.f); u[5] = fmaxf(z1.y + s_b1[5], 0.f);
        u[6] = fmaxf(z1.z + s_b1[6], 0.f); u[7] = fmaxf(z1.w + s_b1[7], 0.f);
        u[8] = fmaxf(z2.x + s_b1[8], 0.f); u[9] = fmaxf(z2.y + s_b1[9], 0.f);
    } else {
#pragma unroll
        for (int f = 0; f < DIM; ++f) u[f] = 0.f;
    }
    float hv[DIM];
#pragma unroll
    for (int f = 0; f < DIM; ++f) hv[f] = s_b2[f];
#pragma unroll
    for (int j = 0; j < DIM; ++j) {
        float uj = u[j];
        const float4* wr = (const float4*)&s_w2[j * 12];
        float4 wa = wr[0], wb = wr[1];
        float2 wc = *(const float2*)&s_w2[j * 12 + 8];
        hv[0] += uj * wa.x; hv[1] += uj * wa.y; hv[2] += uj * wa.z; hv[3] += uj * wa.w;
        hv[4] += uj * wb.x; hv[5] += uj * wb.y; hv[6] += uj * wb.z; hv[7] += uj * wb.w;
        hv[8] += uj * wc.x; hv[9] += uj * wc.y;
    }
#pragma unroll
    for (int f = 0; f < DIM; ++f) hv[f] = valid ? fmaxf(hv[f], 0.f) : 0.f;

    // fused mean-pool accumulation (sum; divide in k_out)
    int lane = tid & 63;
    int g0 = __shfl(g, 0);
    if (__all(g == g0)) {
        float sm[DIM];
#pragma unroll
        for (int f = 0; f < DIM; ++f) {
            float v = hv[f];
            v += __shfl_xor(v, 32); v += __shfl_xor(v, 16); v += __shfl_xor(v, 8);
            v += __shfl_xor(v, 4);  v += __shfl_xor(v, 2);  v += __shfl_xor(v, 1);
            sm[f] = v;
        }
        if (lane < DIM) {
            float sel = sm[0];
#pragma unroll
            for (int f = 1; f < DIM; ++f) sel = (lane == f) ? sm[f] : sel;
            atomicAdd(&poolL[g0 * DIM + lane], sel);
        }
    } else if (valid) {
#pragma unroll
        for (int f = 0; f < DIM; ++f) atomicAdd(&poolL[g * DIM + f], hv[f]);
    }

    if (HAS_NEXT && valid) {
        float pv[DIM];
#pragma unroll
        for (int f = 0; f < DIM; ++f) pv[f] = 0.f;
#pragma unroll
        for (int j = 0; j < DIM; ++j) {
            float hj = hv[j];
            const float4* wr = (const float4*)&s_w1n[j * 12];
            float4 wa = wr[0], wb = wr[1];
            float2 wc = *(const float2*)&s_w1n[j * 12 + 8];
            pv[0] += hj * wa.x; pv[1] += hj * wa.y; pv[2] += hj * wa.z; pv[3] += hj * wa.w;
            pv[4] += hj * wb.x; pv[5] += hj * wb.y; pv[6] += hj * wb.z; pv[7] += hj * wb.w;
            pv[8] += hj * wc.x; pv[9] += hj * wc.y;
        }
        union { __half2 h; unsigned u; } c0, c1, c2, c3, c4;
        c0.h = __floats2half2_rn(pv[0], pv[1]);
        c1.h = __floats2half2_rn(pv[2], pv[3]);
        c2.h = __floats2half2_rn(pv[4], pv[5]);
        c3.h = __floats2half2_rn(pv[6], pv[7]);
        c4.h = __floats2half2_rn(pv[8], pv[9]);
        uint4 s; s.x = c0.u; s.y = c1.u; s.z = c2.u; s.w = c3.u;
        *(uint4*)&pn[n * PH] = s;
        *(unsigned*)&pn[n * PH + 8] = c4.u;
    }
}

__global__ void k_out(const float* __restrict__ pool, const int* __restrict__ gptr,
                      const float* __restrict__ l1, const float* __restrict__ l2,
                      const float* __restrict__ l3, const float* __restrict__ l4,
                      const float* __restrict__ l5, float* __restrict__ out) {
    int t = blockIdx.x * blockDim.x + threadIdx.x;
    if (t >= N_GRAPHS * OUT) return;
    int g = t >> 4;
    int o = t & 15;
    float cnt = fmaxf((float)(gptr[g + 1] - gptr[g]), 1.f);
    const float* ls[5] = {l1, l2, l3, l4, l5};
    float acc = 0.f;
#pragma unroll
    for (int l = 0; l < 5; ++l)
#pragma unroll
        for (int f = 0; f < DIM; ++f)
            acc += pool[(l * N_GRAPHS + g) * DIM + f] * ls[l][f * OUT + o];
    out[t] = tanhf(acc / cnt);
}

extern "C" void kernel_launch(void* const* d_in, const int* in_sizes, int n_in,
                              void* d_out, int out_size, void* d_ws, size_t ws_size,
                              hipStream_t stream) {
    const float* x     = (const float*)d_in[0];
    const int*   ei    = (const int*)d_in[1];
    const int*   batch = (const int*)d_in[2];
    const float *w1[5], *b1[5], *w2[5], *b2[5], *lp[5];
    for (int l = 0; l < 5; ++l) {
        w1[l] = (const float*)d_in[3 + l * 4 + 0];
        b1[l] = (const float*)d_in[3 + l * 4 + 1];
        w2[l] = (const float*)d_in[3 + l * 4 + 2];
        b2[l] = (const float*)d_in[3 + l * 4 + 3];
        lp[l] = (const float*)d_in[23 + l];
    }
    float* out = (float*)d_out;

    // workspace (~26 MB)
    ushort* ptA  = (ushort*)d_ws;                       // N*PH ushorts (3.2MB)
    ushort* ptB  = ptA + N_NODES * PH;                  // 3.2MB
    float*  z    = (float*)(ptB + N_NODES * PH);        // N*ZP floats (4.8MB)
    float*  pool = z + N_NODES * ZP;                    // 25,600 floats
    int*    gptr = (int*)(pool + 5 * N_GRAPHS * DIM);   // 513 -> pad 516
    int*    bbase= gptr + 516;                          // NBUCK+1 -> pad 784
    int*    rowp = bbase + 784;                         // 100,001 -> pad 100,004
    int*    col  = rowp + 100004;                       // N_EDGES
    int*    hist = col + N_EDGES;                       // NBUCK*NBLK_E

    hipMemsetAsync(pool, 0, 5 * N_GRAPHS * DIM * sizeof(float), stream);

    k_bounds<<<NBLK, 256, 0, stream>>>(batch, gptr);
    k_proj1<<<(N_NODES * 64 + 255) / 256, 256, 0, stream>>>(x, w1[0], ptA);

    k_hist<<<NBLK_E, 512, 0, stream>>>(ei, hist);
    k_btot<<<NBUCK, 64, 0, stream>>>(hist, bbase);
    k_bscan<<<1, 1024, 0, stream>>>(bbase, rowp);
    k_colscan<<<NBUCK, NBLK_E, 0, stream>>>(hist, bbase);
    k_bucket<<<NBLK_E, 512, 0, stream>>>(ei, hist, col);
    k_sort<<<NBUCK, 256, 0, stream>>>(bbase, col, rowp);

    ushort* pc  = ptA;
    ushort* pnx = ptB;
    for (int l = 0; l < 5; ++l) {
        float* poolL = pool + l * N_GRAPHS * DIM;
        k_agg<<<(N_NODES * 4 + 255) / 256, 256, 0, stream>>>(pc, rowp, col, z);
        if (l < 4)
            k_mlp<1><<<NBLK, 256, 0, stream>>>(z, batch, b1[l], w2[l], b2[l],
                                               w1[l + 1], poolL, pnx);
        else
            k_mlp<0><<<NBLK, 256, 0, stream>>>(z, batch, b1[l], w2[l], b2[l],
                                               nullptr, poolL, nullptr);
        ushort* tmp = pc; pc = pnx; pnx = tmp;
    }
    k_out<<<(N_GRAPHS * OUT + 255) / 256, 256, 0, stream>>>(
        pool, gptr, lp[0], lp[1], lp[2], lp[3], lp[4], out);
}